// Round 4
// baseline (2925.225 us; speedup 1.0000x reference)
//
#include <hip/hip_runtime.h>
#include <math.h>

#define NN 50000
#define NE 800000
#define NGRAPH 100
#define NPG 500
#define NB_SCAN 196   // ceil(NN/256)

// ---------------- setup kernels ----------------

__global__ void k_deg(const int* __restrict__ col, int* __restrict__ degi) {
    int e = blockIdx.x * blockDim.x + threadIdx.x;
    if (e < NE) atomicAdd(&degi[col[e]], 1);
}

__global__ void k_dh(const int* __restrict__ degi, float* __restrict__ dh) {
    int i = blockIdx.x * blockDim.x + threadIdx.x;
    if (i < NN) {
        int d = degi[i];
        dh[i] = d > 0 ? (float)(1.0 / sqrt((double)d)) : 0.0f;
    }
}

// hierarchical exclusive scan: block sums -> scan sums -> per-block scan
__global__ void k_bsum(const int* __restrict__ degi, int* __restrict__ bsum) {
    __shared__ int sh[256];
    int i = blockIdx.x * 256 + threadIdx.x;
    sh[threadIdx.x] = (i < NN) ? degi[i] : 0;
    __syncthreads();
    for (int s = 128; s > 0; s >>= 1) {
        if (threadIdx.x < s) sh[threadIdx.x] += sh[threadIdx.x + s];
        __syncthreads();
    }
    if (threadIdx.x == 0) bsum[blockIdx.x] = sh[0];
}

__global__ void k_bscan(const int* __restrict__ bsum, int* __restrict__ boff) {
    __shared__ int sh[2][256];
    int v = (threadIdx.x < NB_SCAN) ? bsum[threadIdx.x] : 0;
    int cur = 0;
    sh[0][threadIdx.x] = v;
    __syncthreads();
    for (int s = 1; s < 256; s <<= 1) {
        int val = sh[cur][threadIdx.x];
        if ((int)threadIdx.x >= s) val += sh[cur][threadIdx.x - s];
        sh[cur ^ 1][threadIdx.x] = val;
        cur ^= 1;
        __syncthreads();
    }
    if (threadIdx.x < NB_SCAN) boff[threadIdx.x] = sh[cur][threadIdx.x] - v;
}

__global__ void k_scan2(const int* __restrict__ degi, const int* __restrict__ boff,
                        int* __restrict__ off) {
    __shared__ int sh[2][256];
    int i = blockIdx.x * 256 + threadIdx.x;
    int v = (i < NN) ? degi[i] : 0;
    int cur = 0;
    sh[0][threadIdx.x] = v;
    __syncthreads();
    for (int s = 1; s < 256; s <<= 1) {
        int val = sh[cur][threadIdx.x];
        if ((int)threadIdx.x >= s) val += sh[cur][threadIdx.x - s];
        sh[cur ^ 1][threadIdx.x] = val;
        cur ^= 1;
        __syncthreads();
    }
    if (i < NN) off[i] = boff[blockIdx.x] + sh[cur][threadIdx.x] - v;
}

__global__ void k_fill(const int* __restrict__ row, const int* __restrict__ col,
                       const float* __restrict__ dh, const int* __restrict__ off,
                       int* __restrict__ cursor, int* __restrict__ csr_r,
                       float* __restrict__ csr_w) {
    int e = blockIdx.x * blockDim.x + threadIdx.x;
    if (e >= NE) return;
    int r = row[e], c = col[e];
    int pos = off[c] + atomicAdd(&cursor[c], 1);
    csr_r[pos] = r;
    csr_w[pos] = dh[r] * dh[c];
}

// ---------------- recurrence kernels (all fp32, F=64) ----------------
// 4-slot rotating pool is both ping-pong storage and archive.

// T1 = -A·src  -> slot
__global__ __launch_bounds__(256) void k_init(
    const float* __restrict__ src, const int* __restrict__ off,
    const int* __restrict__ degi, const int* __restrict__ csr_r,
    const float* __restrict__ csr_w, float* __restrict__ Tout) {
    int f = threadIdx.x & 63;
    int node = blockIdx.x * 4 + (threadIdx.x >> 6);
    if (node >= NN) return;
    int s = off[node], e = s + degi[node];
    float g0 = 0.f, g1 = 0.f;
    int i = s;
    for (; i + 7 < e; i += 8) {
        int r0 = csr_r[i],     r1 = csr_r[i + 1], r2 = csr_r[i + 2], r3 = csr_r[i + 3];
        int r4 = csr_r[i + 4], r5 = csr_r[i + 5], r6 = csr_r[i + 6], r7 = csr_r[i + 7];
        float w0 = csr_w[i],     w1 = csr_w[i + 1], w2 = csr_w[i + 2], w3 = csr_w[i + 3];
        float w4 = csr_w[i + 4], w5 = csr_w[i + 5], w6 = csr_w[i + 6], w7 = csr_w[i + 7];
        g0 += w0 * src[r0 * 64 + f] + w1 * src[r1 * 64 + f]
            + w2 * src[r2 * 64 + f] + w3 * src[r3 * 64 + f];
        g1 += w4 * src[r4 * 64 + f] + w5 * src[r5 * 64 + f]
            + w6 * src[r6 * 64 + f] + w7 * src[r7 * 64 + f];
    }
    for (; i < e; ++i) g0 += csr_w[i] * src[csr_r[i] * 64 + f];
    Tout[node * 64 + f] = -(g0 + g1);
}

// Tnext = -2·A·Tcur - Tprev  (all distinct slots / src)
__global__ __launch_bounds__(256) void k_step(
    const float* __restrict__ Tcur, const float* __restrict__ Tprev,
    float* __restrict__ Tnext, const int* __restrict__ off,
    const int* __restrict__ degi, const int* __restrict__ csr_r,
    const float* __restrict__ csr_w) {
    int f = threadIdx.x & 63;
    int node = blockIdx.x * 4 + (threadIdx.x >> 6);
    if (node >= NN) return;
    int s = off[node], e = s + degi[node];
    float g0 = 0.f, g1 = 0.f;
    int i = s;
    for (; i + 7 < e; i += 8) {
        int r0 = csr_r[i],     r1 = csr_r[i + 1], r2 = csr_r[i + 2], r3 = csr_r[i + 3];
        int r4 = csr_r[i + 4], r5 = csr_r[i + 5], r6 = csr_r[i + 6], r7 = csr_r[i + 7];
        float w0 = csr_w[i],     w1 = csr_w[i + 1], w2 = csr_w[i + 2], w3 = csr_w[i + 3];
        float w4 = csr_w[i + 4], w5 = csr_w[i + 5], w6 = csr_w[i + 6], w7 = csr_w[i + 7];
        g0 += w0 * Tcur[r0 * 64 + f] + w1 * Tcur[r1 * 64 + f]
            + w2 * Tcur[r2 * 64 + f] + w3 * Tcur[r3 * 64 + f];
        g1 += w4 * Tcur[r4 * 64 + f] + w5 * Tcur[r5 * 64 + f]
            + w6 * Tcur[r6 * 64 + f] + w7 * Tcur[r7 * 64 + f];
    }
    for (; i < e; ++i) g0 += csr_w[i] * Tcur[csr_r[i] * 64 + f];
    Tnext[node * 64 + f] = -2.f * (g0 + g1) - Tprev[node * 64 + f];
}

// ---------------- combine: acc planes from 4 pool slots ----------------
// mem slot m holds T_{k-3+m} for the block ending at step k (k multiple of 4)

struct CombCfg {
    float c0[4];      // coeff for src0 term (×0.5 applied host-side) [FIRST only]
    float ck[4][4];   // coeffs for pool mem-slots 0..3
    int   plane[4];   // target plane index (stride NN*64) in accb
};

template <int NT, bool FIRST, bool ABS>
__global__ __launch_bounds__(256) void k_combine(
    const float* __restrict__ src0, const float* __restrict__ pool,
    float* __restrict__ accb, CombCfg cfg) {
    int f = threadIdx.x & 63;
    int node = blockIdx.x * 4 + (threadIdx.x >> 6);
    if (node >= NN) return;
    int idx = node * 64 + f;
    float tv[4];
#pragma unroll
    for (int m = 0; m < 4; ++m) tv[m] = pool[(size_t)m * NN * 64 + idx];
    float s0 = FIRST ? src0[idx] : 0.f;
#pragma unroll
    for (int t = 0; t < NT; ++t) {
        size_t o = (size_t)cfg.plane[t] * NN * 64 + idx;
        float a = FIRST ? cfg.c0[t] * s0 : accb[o];
#pragma unroll
        for (int m = 0; m < 4; ++m) a += cfg.ck[t][m] * tv[m];
        if (ABS) a = fabsf(a);
        accb[o] = a;
    }
}

// ---------------- moments ----------------
// cols: [0,64)->x, [64,320)->hacc planes (abs'ed), [320,704)->acc2 planes (abs'ed)
__global__ void k_moments(const float* __restrict__ x, const float* __restrict__ hacc,
                          const float* __restrict__ acc2, float* __restrict__ out) {
    int g = blockIdx.y;
    int col = blockIdx.x * 256 + threadIdx.x;
    if (col >= 704) return;
    const float* src;
    int c0;
    if (col < 64)       { src = x;    c0 = col; }
    else if (col < 320) { int p = (col - 64) >> 6;  src = hacc + (size_t)p * NN * 64; c0 = (col - 64) & 63; }
    else                { int p = (col - 320) >> 6; src = acc2 + (size_t)p * NN * 64; c0 = (col - 320) & 63; }
    double s1 = 0, s2 = 0, s3 = 0, s4 = 0;
    int base = g * NPG;
    for (int i = 0; i < NPG; ++i) {
        double v = (double)src[(size_t)(base + i) * 64 + c0];
        double v2 = v * v;
        s1 += v; s2 += v2; s3 += v2 * v; s4 += v2 * v2;
    }
    double n = (double)NPG;
    double mu = s1 / n;
    double E2 = s2 / n, E3 = s3 / n, E4 = s4 / n;
    double m2 = E2 - mu * mu;
    double m3 = E3 - 3.0 * mu * E2 + 2.0 * mu * mu * mu;
    double m4 = E4 - 4.0 * mu * E3 + 6.0 * mu * mu * E2 - 3.0 * mu * mu * mu * mu;
    float m2f = (float)m2;
    float skew = 0.f, kurt = -3.f;
    if (m2f > 0.f) {
        skew = (float)(m3 / (m2 * sqrt(m2)));
        if (skew > 1e15f) skew = 0.f;
        kurt = (float)(m4 / (m2 * m2) - 3.0);
        if (kurt > 1e15f) kurt = -3.f;
    }
    size_t ob = (size_t)g * 2816 + col;
    out[ob]        = (float)mu;
    out[ob + 704]  = m2f;
    out[ob + 1408] = skew;
    out[ob + 2112] = kurt;
}

// ---------------- host ----------------

extern "C" void kernel_launch(void* const* d_in, const int* in_sizes, int n_in,
                              void* d_out, int out_size, void* d_ws, size_t ws_size,
                              hipStream_t stream) {
    const float* x = (const float*)d_in[0];
    const int* ei  = (const int*)d_in[1];
    const int* row = ei;
    const int* col = ei + NE;
    float* out = (float*)d_out;

    // Chebyshev coefficients [17][4], double precision (matches numpy)
    float C[17][4];
    {
        const int Nc = 17;
        const int scales[4] = {2, 4, 8, 16};
        for (int si = 0; si < 4; ++si) {
            double ker[17];
            for (int j = 0; j < Nc; ++j) {
                double num = cos(M_PI * (j + 0.5) / Nc);
                double b = -num;   // 1 - (num + 1)
                double v = pow(b, (double)(scales[si] / 2)) - pow(b, (double)scales[si]);
                if (v < 0) v = 0;
                ker[j] = sqrt(v);
            }
            for (int o = 0; o < Nc; ++o) {
                double acc = 0;
                for (int j = 0; j < Nc; ++j) acc += ker[j] * cos(M_PI * o * (j + 0.5) / Nc);
                C[o][si] = (float)(2.0 / Nc * acc);
            }
        }
    }

    // workspace carve (~186 MB)
    char* p = (char*)d_ws;
    auto alloc = [&](size_t bytes) -> void* {
        void* r = (void*)p;
        p += (bytes + 255) & ~(size_t)255;
        return r;
    };
    int*   degi   = (int*)alloc((size_t)NN * 4);
    float* dh     = (float*)alloc((size_t)NN * 4);
    int*   off    = (int*)alloc((size_t)NN * 4);
    int*   cursor = (int*)alloc((size_t)NN * 4);
    int*   bsum   = (int*)alloc((size_t)NB_SCAN * 4);
    int*   boff   = (int*)alloc((size_t)NB_SCAN * 4);
    int*   csr_r  = (int*)alloc((size_t)NE * 4);
    float* csr_w  = (float*)alloc((size_t)NE * 4);
    float* pool   = (float*)alloc((size_t)4 * NN * 64 * 4);  // 51.2 MB rotating T slots
    float* hacc   = (float*)alloc((size_t)4 * NN * 64 * 4);  // 51.2 MB |h| planes
    float* acc2   = (float*)alloc((size_t)6 * NN * 64 * 4);  // 76.8 MB |d2| planes
    if ((size_t)(p - (char*)d_ws) > ws_size) return;

    hipMemsetAsync(degi, 0, (size_t)NN * 4, stream);
    hipMemsetAsync(cursor, 0, (size_t)NN * 4, stream);

    k_deg  <<<(NE + 255) / 256, 256, 0, stream>>>(col, degi);
    k_dh   <<<(NN + 255) / 256, 256, 0, stream>>>(degi, dh);
    k_bsum <<<NB_SCAN, 256, 0, stream>>>(degi, bsum);
    k_bscan<<<1, 256, 0, stream>>>(bsum, boff);
    k_scan2<<<NB_SCAN, 256, 0, stream>>>(degi, boff, off);
    k_fill <<<(NE + 255) / 256, 256, 0, stream>>>(row, col, dh, off, cursor, csr_r, csr_w);

    const int g1 = (NN + 3) / 4;
    auto slot = [&](int k) { return pool + (size_t)((k - 1) & 3) * NN * 64; };

    // run one chain: src -> accumulate Σ c_k T_k into planes of accb
    auto run_chain = [&](const float* src, float* accb, const int* scl, const int* pln, int nt) {
        k_init<<<g1, 256, 0, stream>>>(src, off, degi, csr_r, csr_w, slot(1));
        for (int k = 2; k <= 16; ++k) {
            const float* Tprev = (k == 2) ? src : slot(k - 2);
            k_step<<<g1, 256, 0, stream>>>(slot(k - 1), Tprev, slot(k),
                                           off, degi, csr_r, csr_w);
            if ((k & 3) == 0) {   // combine T_{k-3..k}
                CombCfg cfg;
                for (int t = 0; t < nt; ++t) {
                    int si = scl[t];
                    cfg.c0[t] = 0.5f * C[0][si];
                    cfg.plane[t] = pln[t];
                    for (int m = 0; m < 4; ++m) cfg.ck[t][m] = C[k - 3 + m][si];
                }
                bool first = (k == 4), last = (k == 16);
                if (first) {
                    if (nt == 4) k_combine<4, true, false><<<g1, 256, 0, stream>>>(src, pool, accb, cfg);
                    if (nt == 3) k_combine<3, true, false><<<g1, 256, 0, stream>>>(src, pool, accb, cfg);
                    if (nt == 2) k_combine<2, true, false><<<g1, 256, 0, stream>>>(src, pool, accb, cfg);
                    if (nt == 1) k_combine<1, true, false><<<g1, 256, 0, stream>>>(src, pool, accb, cfg);
                } else if (last) {
                    if (nt == 4) k_combine<4, false, true><<<g1, 256, 0, stream>>>(nullptr, pool, accb, cfg);
                    if (nt == 3) k_combine<3, false, true><<<g1, 256, 0, stream>>>(nullptr, pool, accb, cfg);
                    if (nt == 2) k_combine<2, false, true><<<g1, 256, 0, stream>>>(nullptr, pool, accb, cfg);
                    if (nt == 1) k_combine<1, false, true><<<g1, 256, 0, stream>>>(nullptr, pool, accb, cfg);
                } else {
                    if (nt == 4) k_combine<4, false, false><<<g1, 256, 0, stream>>>(nullptr, pool, accb, cfg);
                    if (nt == 3) k_combine<3, false, false><<<g1, 256, 0, stream>>>(nullptr, pool, accb, cfg);
                    if (nt == 2) k_combine<2, false, false><<<g1, 256, 0, stream>>>(nullptr, pool, accb, cfg);
                    if (nt == 1) k_combine<1, false, false><<<g1, 256, 0, stream>>>(nullptr, pool, accb, cfg);
                }
            }
        }
    };

    // ---- phase 1: x -> hacc planes 0..3 (|h| per scale) ----
    {
        const int scl[4] = {0, 1, 2, 3};
        const int pln[4] = {0, 1, 2, 3};
        run_chain(x, hacc, scl, pln, 4);
    }

    // ---- phase 2: 3 independent chains on hacc planes 0..2 ----
    // FENG targets: s1=0 -> s2 {1,2,3} planes {0,1,3}; s1=1 -> {2,3}->{2,4}; s1=2 -> {3}->{5}
    {
        const int scl0[3] = {1, 2, 3}; const int pln0[3] = {0, 1, 3};
        run_chain(hacc + (size_t)0 * NN * 64, acc2, scl0, pln0, 3);
        const int scl1[2] = {2, 3};    const int pln1[2] = {2, 4};
        run_chain(hacc + (size_t)1 * NN * 64, acc2, scl1, pln1, 2);
        const int scl2[1] = {3};       const int pln2[1] = {5};
        run_chain(hacc + (size_t)2 * NN * 64, acc2, scl2, pln2, 1);
    }

    // ---- moments ----
    dim3 mg(3, NGRAPH);
    k_moments<<<mg, 256, 0, stream>>>(x, hacc, acc2, out);
}